// Round 1
// baseline (80.937 us; speedup 1.0000x reference)
//
#include <hip/hip_runtime.h>

#define BB 16
#define SS 2048
#define DD 64
#define OO 128
#define SPL 16
#define YEL (OO * DD)   // 8192 elems per Y[b] (and per slab)

typedef __attribute__((ext_vector_type(8))) short short8;   // 8 bf16 = 4 VGPRs
typedef __attribute__((ext_vector_type(4))) float f32x4;

__device__ __forceinline__ unsigned short f2bf(float f) {   // RNE fp32->bf16
    unsigned int u = __float_as_uint(f);
    return (unsigned short)((u + 0x7FFF + ((u >> 16) & 1)) >> 16);
}
__device__ __forceinline__ unsigned int pk2(float x, float y) {
    return (unsigned int)f2bf(x) | ((unsigned int)f2bf(y) << 16);
}
__device__ __forceinline__ short8 cvt8(float4 a, float4 b) {
    uint4 u = make_uint4(pk2(a.x, a.y), pk2(a.z, a.w), pk2(b.x, b.y), pk2(b.z, b.w));
    return *(short8*)&u;
}
__device__ __forceinline__ float bflo(unsigned int u) { return __uint_as_float(u << 16); }
__device__ __forceinline__ float bfhi(unsigned int u) { return __uint_as_float(u & 0xffff0000u); }

// ---------------------------------------------------------------------------
// k_yf (R5-verified body): slab[b][p] = partial Y over 128-t slice.
// Store layout is now LINEAR [o][d] (no swizzle needed: consumer reads from
// global/L2, not LDS). grid 256 = (b = bx&15, p = bx>>4), 512 thr.
// ---------------------------------------------------------------------------
__global__ __launch_bounds__(512) void k_yf(const float* __restrict__ X,
                                            const float* __restrict__ W,
                                            unsigned short* __restrict__ YpB) {
    __shared__ unsigned short XT[64 * 132];

    const int bx  = blockIdx.x;
    const int b   = bx & 15;
    const int p   = bx >> 4;
    const int t0  = p * (SS / SPL);
    const int tid = threadIdx.x;
    const int w   = tid >> 6;
    const int l   = tid & 63;

    const float* Xb = X + ((size_t)b * SS + t0) * DD;
#pragma unroll
    for (int i = 0; i < 4; ++i) {
        const int tl = w * 4 + i * 32;
        const float x0 = Xb[(size_t)(tl + 0) * DD + l];
        const float x1 = Xb[(size_t)(tl + 1) * DD + l];
        const float x2 = Xb[(size_t)(tl + 2) * DD + l];
        const float x3 = Xb[(size_t)(tl + 3) * DD + l];
        *(uint2*)&XT[l * 132 + tl] = make_uint2(pk2(x0, x1), pk2(x2, x3));
    }
    __syncthreads();

    const int n = l & 15;
    const int q = l >> 4;

    f32x4 acc[4];
#pragma unroll
    for (int j = 0; j < 4; ++j) acc[j] = {0.f, 0.f, 0.f, 0.f};

    const float* Wr = W + (size_t)(w * 16 + n) * SS + t0;
#pragma unroll
    for (int kk = 0; kk < SS / SPL; kk += 32) {
        const float4 wa = *(const float4*)(Wr + kk + q * 8);
        const float4 wb = *(const float4*)(Wr + kk + q * 8 + 4);
        const short8 a  = cvt8(wa, wb);
#pragma unroll
        for (int j = 0; j < 4; ++j) {
            const unsigned short* r = &XT[(j * 16 + n) * 132 + kk + q * 8];
            const uint2 lo = *(const uint2*)(r);
            const uint2 hi = *(const uint2*)(r + 4);
            uint4 u = make_uint4(lo.x, lo.y, hi.x, hi.y);
            acc[j] = __builtin_amdgcn_mfma_f32_16x16x32_bf16(a, *(short8*)&u, acc[j], 0, 0, 0);
        }
    }

    unsigned short* slab = YpB + (size_t)(b * SPL + p) * YEL;
#pragma unroll
    for (int j = 0; j < 4; ++j)
#pragma unroll
        for (int r = 0; r < 4; ++r)
            slab[((w * 16 + q * 4 + r) << 6) + (j * 16 + n)] = f2bf(acc[j][r]);
}

// ---------------------------------------------------------------------------
// k_red: ONE reduction of the 16 bf16 slabs per batch -> Yf[b] (linear bf16
// [o][d]). Replaces the 16x-redundant per-block reduction in the old k_out2.
// 16384 threads = 16 batches * 1024 uint4-chunks; grid 128 x 128 thr.
// ---------------------------------------------------------------------------
__global__ __launch_bounds__(128) void k_red(const unsigned short* __restrict__ YpB,
                                             unsigned short* __restrict__ Yf) {
    const int t = blockIdx.x * 128 + threadIdx.x;   // 0..16383
    const int b = t >> 10;
    const int c = t & 1023;

    const uint4* src = (const uint4*)YpB + (size_t)b * SPL * (YEL / 8) + c;
    float s[8];
#pragma unroll
    for (int e = 0; e < 8; ++e) s[e] = 0.f;
#pragma unroll
    for (int pp = 0; pp < SPL; ++pp) {
        const uint4 v = src[(size_t)pp * (YEL / 8)];
        s[0] += bflo(v.x); s[1] += bfhi(v.x);
        s[2] += bflo(v.y); s[3] += bfhi(v.y);
        s[4] += bflo(v.z); s[5] += bfhi(v.z);
        s[6] += bflo(v.w); s[7] += bfhi(v.w);
    }
    ((uint4*)Yf)[t] = make_uint4(pk2(s[0], s[1]), pk2(s[2], s[3]),
                                 pk2(s[4], s[5]), pk2(s[6], s[7]));
}

// ---------------------------------------------------------------------------
// k_out: out[b, st*64.., :] = X @ Y^T + bias (R8-verified MFMA math).
// LDS-free: B-frags read directly from Yf (16KB/batch, L2-resident), no
// barrier. grid 512 = (b = bx>>5, st = bx&31), 256 thr -> 2 blocks/CU.
// ---------------------------------------------------------------------------
__global__ __launch_bounds__(256) void k_out(const float* __restrict__ X,
                                             const unsigned short* __restrict__ Yf,
                                             const float* __restrict__ bias,
                                             float* __restrict__ out) {
    const int bx  = blockIdx.x;
    const int b   = bx >> 5;
    const int st  = bx & 31;
    const int tid = threadIdx.x;
    const int w   = tid >> 6;      // 0..3
    const int l   = tid & 63;
    const int n   = l & 15;
    const int q   = l >> 4;

    const int row0 = st * 64 + w * 16;

    float bv[8];
#pragma unroll
    for (int j = 0; j < 8; ++j) bv[j] = bias[j * 16 + n];

    f32x4 acc[8];
#pragma unroll
    for (int j = 0; j < 8; ++j) acc[j] = {0.f, 0.f, 0.f, 0.f};

    const unsigned short* Yb = Yf + (size_t)b * YEL;
    const float* Xr = X + ((size_t)b * SS + row0 + n) * DD;
#pragma unroll
    for (int kk = 0; kk < DD; kk += 32) {
        const float4 xa = *(const float4*)(Xr + kk + q * 8);
        const float4 xb = *(const float4*)(Xr + kk + q * 8 + 4);
        const short8 a  = cvt8(xa, xb);
        const int c8    = (kk >> 3) + q;
#pragma unroll
        for (int j = 0; j < 8; ++j) {
            const int o = j * 16 + n;
            const uint4 u = *(const uint4*)&Yb[(o << 6) + (c8 << 3)];
            acc[j] = __builtin_amdgcn_mfma_f32_16x16x32_bf16(a, *(short8*)&u, acc[j], 0, 0, 0);
        }
    }

    float* op = out + ((size_t)b * SS + row0 + q * 4) * OO;
#pragma unroll
    for (int j = 0; j < 8; ++j)
#pragma unroll
        for (int r = 0; r < 4; ++r)
            op[(size_t)r * OO + j * 16 + n] = acc[j][r] + bv[j];
}

extern "C" void kernel_launch(void* const* d_in, const int* in_sizes, int n_in,
                              void* d_out, int out_size, void* d_ws, size_t ws_size,
                              hipStream_t stream) {
    const float* X    = (const float*)d_in[0];  // [B,S,D]
    const float* W    = (const float*)d_in[1];  // [OUT,S]
    const float* bias = (const float*)d_in[2];  // [OUT]
    float* out = (float*)d_out;                 // [B,S,OUT]

    unsigned short* YpB = (unsigned short*)d_ws;                   // [B*SPL][YEL] bf16 slabs, 4.19MB
    unsigned short* Yf  = YpB + (size_t)BB * SPL * YEL;            // [B][YEL] reduced bf16 Y, 262KB

    k_yf <<<dim3(256), dim3(512), 0, stream>>>(X, W, YpB);
    k_red<<<dim3(128), dim3(128), 0, stream>>>(YpB, Yf);
    k_out<<<dim3(512), dim3(256), 0, stream>>>(X, Yf, bias, out);
}